// Round 4
// baseline (3863.046 us; speedup 1.0000x reference)
//
#include <hip/hip_runtime.h>
#include <cstdint>
#include <cstddef>

#define NPTS 8192
#define NB 8
#define NS 2048
#define KG 32
#define NROWS (NB*NS*KG)   // 524288
#define NREP 32            // stats atomic replication

// Distance with NO fma contraction: bitwise-identical to numpy f32
// ((dx*dx + dy*dy) + dz*dz).
__device__ __forceinline__ float dist2_exact(float ax, float ay, float az,
                                             float bx, float by, float bz)
{
#pragma clang fp contract(off)
  float dx = ax - bx;
  float dy = ay - by;
  float dz = az - bz;
  return dx * dx + dy * dy + dz * dz;
}

// ======================== FPS ========================
// One block per batch, 512 threads x 16 pts in regs. Hot phase carries NO
// index: per-thread running max of min-dists (f32), f32 butterfly + LDS
// partials for the block max, then a cheap equality-scan resolves the
// argmax index (first-occurrence = global min index) via LDS atomicMin.
__launch_bounds__(512)
__global__ void fps_kernel(const float* __restrict__ xyz, float* __restrict__ cents)
{
  __shared__ float sx[NPTS], sy[NPTS], sz[NPTS];       // 96 KB
  __shared__ float smax[2][8];
  __shared__ unsigned scand[2];

  const int b = blockIdx.x;
  const int t = threadIdx.x;
  const float* base = xyz + (size_t)b * NPTS * 3;

  float px[16], py[16], pz[16], dmin[16];
#pragma unroll
  for (int j = 0; j < 16; ++j) {
    int i = j * 512 + t;
    float x = base[3*i+0], y = base[3*i+1], z = base[3*i+2];
    px[j] = x; py[j] = y; pz[j] = z;
    dmin[j] = 1e10f;
    sx[i] = x; sy[i] = y; sz[i] = z;
  }

  float cx = base[0], cy = base[1], cz = base[2];
  if (t == 0) {
    float* c0 = cents + (size_t)b * NS * 3;
    c0[0] = cx; c0[1] = cy; c0[2] = cz;
    scand[0] = 0xFFFFFFFFu;
    scand[1] = 0xFFFFFFFFu;
  }
  __syncthreads();   // coords staged, scand init

  for (int it = 1; it < NS; ++it) {
    const int pb = it & 1;
    // ---- phase 1: update dmin, track per-thread max (10 VALU/pt)
    float bm = 0.f;
#pragma unroll
    for (int j = 0; j < 16; ++j) {
      float d = dist2_exact(px[j], py[j], pz[j], cx, cy, cz);
      float m = fminf(dmin[j], d);
      dmin[j] = m;
      bm = fmaxf(bm, m);
    }
    // ---- wave butterfly on f32
#pragma unroll
    for (int off = 1; off <= 32; off <<= 1)
      bm = fmaxf(bm, __shfl_xor(bm, off, 64));
    if ((t & 63) == 0) smax[pb][t >> 6] = bm;
    __syncthreads();                    // B1
    if (t == 0) scand[pb ^ 1] = 0xFFFFFFFFu;   // re-init other buffer (safe: ≥2 barriers from its readers)
    float bmax = smax[pb][0];
#pragma unroll
    for (int q = 1; q < 8; ++q) bmax = fmaxf(bmax, smax[pb][q]);
    // ---- index resolution: lowest i with dmin == bmax
    unsigned cand = 0xFFFFFFFFu;
#pragma unroll
    for (int j = 15; j >= 0; --j)
      cand = (dmin[j] == bmax) ? (unsigned)(j * 512 + t) : cand;
    if (cand != 0xFFFFFFFFu) atomicMin(&scand[pb], cand);
    __syncthreads();                    // B2
    const int win = (int)scand[pb];
    cx = sx[win]; cy = sy[win]; cz = sz[win];   // same-address broadcast
    if (t == 0) {
      float* cp = cents + ((size_t)b * NS + it) * 3;
      cp[0] = cx; cp[1] = cy; cp[2] = cz;
    }
  }
}

// ======================== Ball query ========================
__launch_bounds__(256)
__global__ void ballq_kernel(const float* __restrict__ xyz,
                             const float* __restrict__ cents,
                             int* __restrict__ gidx)
{
  const int gid  = blockIdx.x * 256 + threadIdx.x;
  const int w    = gid >> 6;          // centroid id 0..16383
  const int lane = gid & 63;
  const int b    = w >> 11;
  const float* base = xyz + (size_t)b * NPTS * 3;
  const float cx = cents[3*w+0], cy = cents[3*w+1], cz = cents[3*w+2];
  const float R2 = (float)(0.2 * 0.2);
  int* out = gidx + (size_t)w * KG;

  int filled = 0, first = -1;
  for (int c = 0; c < NPTS/64; ++c) {
    int i = (c << 6) | lane;
    float d = dist2_exact(base[3*i+0], base[3*i+1], base[3*i+2], cx, cy, cz);
    bool inb = (d <= R2);
    unsigned long long mask = __ballot(inb);
    if (first < 0 && mask) first = (c << 6) + (__ffsll((long long)mask) - 1);
    int pre  = __popcll(mask & ((1ull << lane) - 1ull));
    int slot = filled + pre;
    if (inb && slot < KG) out[slot] = i;
    filled += __popcll(mask);
    if (filled >= KG) break;
  }
  if (filled < KG && lane < KG && lane >= filled) out[lane] = first;
}

// ======================== shuffle fold-reductions ========================
template<int H>
__device__ __forceinline__ void fold_sum_step(float* a, int lane) {
#pragma unroll
  for (int q = 0; q < H; ++q) {
    float keep = (lane & H) ? a[q + H] : a[q];
    float send = (lane & H) ? a[q] : a[q + H];
    a[q] = keep + __shfl_xor(send, H, 64);
  }
}

__device__ __forceinline__ float fold_sum16(float* a, int lane) {
  fold_sum_step<8>(a, lane);
  fold_sum_step<4>(a, lane);
  fold_sum_step<2>(a, lane);
  fold_sum_step<1>(a, lane);
  float v = a[0];
  v += __shfl_xor(v, 16, 64);
  v += __shfl_xor(v, 32, 64);
  return v;
}

template<int H>
__device__ __forceinline__ void fold_max_step(float* a, int lane) {
#pragma unroll
  for (int q = 0; q < H; ++q) {
    float keep = (lane & H) ? a[q + H] : a[q];
    float send = (lane & H) ? a[q] : a[q + H];
    a[q] = fmaxf(keep, __shfl_xor(send, H, 64));
  }
}

__device__ __forceinline__ float fold_max16(float* a, int lane) {
  fold_max_step<8>(a, lane);
  fold_max_step<4>(a, lane);
  fold_max_step<2>(a, lane);
  fold_max_step<1>(a, lane);
  float v = a[0];
  v = fmaxf(v, __shfl_xor(v, 16, 64));
  return v;
}

// s1/s2 stats of 16 channels (o0 may be dynamic). Destroys y.
__device__ __forceinline__ void stats16(float* y, int lane, int o0,
                                        float* __restrict__ gs1,
                                        float* __restrict__ gs2)
{
  float sq[16];
#pragma unroll
  for (int q = 0; q < 16; ++q) sq[q] = y[q] * y[q];
  float s1 = fold_sum16(y, lane);
  float s2 = fold_sum16(sq, lane);
  if (lane < 16)       atomicAdd(&gs1[o0 + lane], s1);
  else if (lane < 32)  atomicAdd(&gs2[o0 + (lane & 15)], s2);
}

// ======================== cached-activation path ========================
// stats layout (floats): L0 s1@0 s2@2048 | L1 s1@4096 s2@6144 | L2 s1@8192 s2@12288
// prm: a0@0 sh0@64 a1@128 sh1@192 a2@256 sh2@384.

// K1: gather + dense0 + stats0 + store raw L0
__launch_bounds__(256, 3)
__global__ void k1_kernel(const float* __restrict__ xyz, const float* __restrict__ feats,
                          const float* __restrict__ cents, const int* __restrict__ gidx,
                          const float* __restrict__ w0, const float* __restrict__ b0,
                          float* __restrict__ stats, float* __restrict__ actA)
{
  const int t = threadIdx.x, lane = t & 63;
  const int r = blockIdx.x * 256 + t;
  const int b = r >> 16, cs = r >> 5;
  const int i = gidx[r];
  const int rep = (blockIdx.x * 4 + (t >> 6)) & (NREP - 1);
  const float* pp = xyz + ((size_t)(b << 13) + i) * 3;
  const float* cc = cents + (size_t)cs * 3;
  const float* fb = feats + (((size_t)(b << 13) + i) << 6);

  float xin[67];
  xin[0] = pp[0] - cc[0]; xin[1] = pp[1] - cc[1]; xin[2] = pp[2] - cc[2];
  const float4* f4 = (const float4*)fb;
#pragma unroll
  for (int q = 0; q < 16; ++q) {
    float4 v = f4[q];
    xin[3+4*q+0] = v.x; xin[3+4*q+1] = v.y; xin[3+4*q+2] = v.z; xin[3+4*q+3] = v.w;
  }

  float* arow = actA + (size_t)r * 64;
  for (int o0 = 0; o0 < 64; o0 += 16) {     // rolled: ~8.6 KB body, I$-resident
    float y[16];
#pragma unroll
    for (int k = 0; k < 16; ++k) {
      float a = b0[o0 + k];
#pragma unroll
      for (int c = 0; c < 67; ++c)
        a = fmaf(w0[(o0 + k)*67 + c], xin[c], a);
      y[k] = a;
    }
#pragma unroll
    for (int k = 0; k < 16; k += 4)
      *(float4*)(arow + o0 + k) = make_float4(y[k], y[k+1], y[k+2], y[k+3]);
    stats16(y, lane, o0, stats + (size_t)rep*64, stats + 2048 + (size_t)rep*64);
  }
}

// K2: read L0, norm0+relu, dense1 + stats1 + store raw L1
__launch_bounds__(256, 3)
__global__ void k2_kernel(const float* __restrict__ actA,
                          const float* __restrict__ w1, const float* __restrict__ b1,
                          const float* __restrict__ prm,
                          float* __restrict__ stats, float* __restrict__ actB)
{
  const int t = threadIdx.x, lane = t & 63;
  const int r = blockIdx.x * 256 + t;
  const int rep = (blockIdx.x * 4 + (t >> 6)) & (NREP - 1);

  float x[64];
  const float4* in4 = (const float4*)(actA + (size_t)r * 64);
#pragma unroll
  for (int q = 0; q < 16; ++q) {
    float4 v = in4[q];
    x[4*q+0] = v.x; x[4*q+1] = v.y; x[4*q+2] = v.z; x[4*q+3] = v.w;
  }
#pragma unroll
  for (int c = 0; c < 64; ++c)
    x[c] = fmaxf(fmaf(prm[c], x[c], prm[64 + c]), 0.f);

  float* brow = actB + (size_t)r * 64;
  for (int o0 = 0; o0 < 64; o0 += 16) {     // rolled
    float y[16];
#pragma unroll
    for (int k = 0; k < 16; ++k) {
      float a = b1[o0 + k];
#pragma unroll
      for (int c = 0; c < 64; ++c)
        a = fmaf(w1[(o0 + k)*64 + c], x[c], a);
      y[k] = a;
    }
#pragma unroll
    for (int k = 0; k < 16; k += 4)
      *(float4*)(brow + o0 + k) = make_float4(y[k], y[k+1], y[k+2], y[k+3]);
    stats16(y, lane, o0, stats + 4096 + (size_t)rep*64, stats + 6144 + (size_t)rep*64);
  }
}

// K3: read L1, norm1+relu, dense2 + stats2 (no store)
__launch_bounds__(256, 3)
__global__ void k3_kernel(const float* __restrict__ actB,
                          const float* __restrict__ w2, const float* __restrict__ b2,
                          const float* __restrict__ prm,
                          float* __restrict__ stats)
{
  const int t = threadIdx.x, lane = t & 63;
  const int r = blockIdx.x * 256 + t;
  const int rep = (blockIdx.x * 4 + (t >> 6)) & (NREP - 1);

  float x[64];
  const float4* in4 = (const float4*)(actB + (size_t)r * 64);
#pragma unroll
  for (int q = 0; q < 16; ++q) {
    float4 v = in4[q];
    x[4*q+0] = v.x; x[4*q+1] = v.y; x[4*q+2] = v.z; x[4*q+3] = v.w;
  }
#pragma unroll
  for (int c = 0; c < 64; ++c)
    x[c] = fmaxf(fmaf(prm[128 + c], x[c], prm[192 + c]), 0.f);

  for (int o0 = 0; o0 < 128; o0 += 16) {    // rolled
    float y[16];
#pragma unroll
    for (int k = 0; k < 16; ++k) {
      float a = b2[o0 + k];
#pragma unroll
      for (int c = 0; c < 64; ++c)
        a = fmaf(w2[(o0 + k)*64 + c], x[c], a);
      y[k] = a;
    }
    stats16(y, lane, o0, stats + 8192 + (size_t)rep*128, stats + 12288 + (size_t)rep*128);
  }
}

// K4: read L1, norm1+relu, dense2, norm2+relu, k-group max, store out
__launch_bounds__(256, 3)
__global__ void k4_kernel(const float* __restrict__ actB,
                          const float* __restrict__ w2, const float* __restrict__ b2,
                          const float* __restrict__ prm,
                          float* __restrict__ outp)
{
  const int t = threadIdx.x, lane = t & 63;
  const int r = blockIdx.x * 256 + t;
  const int cs = r >> 5;

  float x[64];
  const float4* in4 = (const float4*)(actB + (size_t)r * 64);
#pragma unroll
  for (int q = 0; q < 16; ++q) {
    float4 v = in4[q];
    x[4*q+0] = v.x; x[4*q+1] = v.y; x[4*q+2] = v.z; x[4*q+3] = v.w;
  }
#pragma unroll
  for (int c = 0; c < 64; ++c)
    x[c] = fmaxf(fmaf(prm[128 + c], x[c], prm[192 + c]), 0.f);

  for (int o0 = 0; o0 < 128; o0 += 16) {    // rolled
    float y[16];
#pragma unroll
    for (int k = 0; k < 16; ++k) {
      float a = b2[o0 + k];
#pragma unroll
      for (int c = 0; c < 64; ++c)
        a = fmaf(w2[(o0 + k)*64 + c], x[c], a);
      y[k] = a;
    }
#pragma unroll
    for (int k = 0; k < 16; ++k)
      y[k] = fmaxf(fmaf(prm[256 + o0 + k], y[k], prm[384 + o0 + k]), 0.f);
    float m = fold_max16(y, lane);
    if (!(lane & 16))
      outp[(size_t)cs * 128 + o0 + (lane & 15)] = m;
  }
}

// ======================== fallback recompute path (R3, proven) ========================
template<int MODE>
__launch_bounds__(256, (MODE <= 2 ? 4 : 2))
__global__ void chain_kernel(const float* __restrict__ xyz,
                             const float* __restrict__ feats,
                             const float* __restrict__ cents,
                             const int* __restrict__ gidx,
                             const float* __restrict__ w0, const float* __restrict__ b0,
                             const float* __restrict__ w1, const float* __restrict__ b1,
                             const float* __restrict__ w2, const float* __restrict__ b2,
                             const float* __restrict__ prm,
                             float* __restrict__ stats,
                             float* __restrict__ outp)
{
  const int t    = threadIdx.x;
  const int lane = t & 63;
  const int r    = blockIdx.x * 256 + t;
  const int b    = r >> 16;
  const int cs   = r >> 5;
  const int i    = gidx[r];
  const int rep  = (blockIdx.x * 4 + (t >> 6)) & (NREP - 1);

  const float* pp = xyz + ((size_t)(b << 13) + i) * 3;
  const float* cc = cents + (size_t)cs * 3;
  const float* fb = feats + (((size_t)(b << 13) + i) << 6);

  float acc[64];
  {
    float c0 = pp[0] - cc[0], c1 = pp[1] - cc[1], c2 = pp[2] - cc[2];
#pragma unroll
    for (int o = 0; o < 64; ++o)
      acc[o] = fmaf(w0[o*67+2], c2, fmaf(w0[o*67+1], c1, fmaf(w0[o*67+0], c0, b0[o])));
  }
  for (int c0 = 0; c0 < 64; c0 += 16) {
    float xc[16];
    const float4* f4 = (const float4*)(fb + c0);
    float4 v0 = f4[0], v1 = f4[1], v2 = f4[2], v3 = f4[3];
    xc[0]=v0.x; xc[1]=v0.y; xc[2]=v0.z; xc[3]=v0.w;
    xc[4]=v1.x; xc[5]=v1.y; xc[6]=v1.z; xc[7]=v1.w;
    xc[8]=v2.x; xc[9]=v2.y; xc[10]=v2.z; xc[11]=v2.w;
    xc[12]=v3.x; xc[13]=v3.y; xc[14]=v3.z; xc[15]=v3.w;
#pragma unroll
    for (int o = 0; o < 64; ++o) {
      float a = acc[o];
#pragma unroll
      for (int ci = 0; ci < 16; ++ci)
        a = fmaf(w0[o*67 + 3 + c0 + ci], xc[ci], a);
      acc[o] = a;
    }
  }

  if (MODE == 1) {
#pragma unroll
    for (int o0 = 0; o0 < 64; o0 += 16) {
      float y[16];
#pragma unroll
      for (int q = 0; q < 16; ++q) y[q] = acc[o0 + q];
      stats16(y, lane, o0, stats + (size_t)rep*64, stats + 2048 + (size_t)rep*64);
    }
    return;
  }

#pragma unroll
  for (int o = 0; o < 64; ++o)
    acc[o] = fmaxf(fmaf(prm[o], acc[o], prm[64 + o]), 0.f);

  if (MODE == 2) {
    for (int o0 = 0; o0 < 64; o0 += 16) {
      float y[16];
#pragma unroll
      for (int k = 0; k < 16; ++k) {
        float a = b1[o0 + k];
#pragma unroll
        for (int c = 0; c < 64; ++c)
          a = fmaf(w1[(o0 + k)*64 + c], acc[c], a);
        y[k] = a;
      }
      stats16(y, lane, o0, stats + 4096 + (size_t)rep*64, stats + 6144 + (size_t)rep*64);
    }
    return;
  }

  float y1[64];
#pragma unroll
  for (int o = 0; o < 64; ++o) {
    float a = b1[o];
#pragma unroll
    for (int c = 0; c < 64; ++c)
      a = fmaf(w1[o*64 + c], acc[c], a);
    y1[o] = a;
  }
#pragma unroll
  for (int o = 0; o < 64; ++o)
    y1[o] = fmaxf(fmaf(prm[128 + o], y1[o], prm[192 + o]), 0.f);

  if (MODE == 3) {
    for (int o0 = 0; o0 < 128; o0 += 16) {
      float y[16];
#pragma unroll
      for (int k = 0; k < 16; ++k) {
        float a = b2[o0 + k];
#pragma unroll
        for (int c = 0; c < 64; ++c)
          a = fmaf(w2[(o0 + k)*64 + c], y1[c], a);
        y[k] = a;
      }
      stats16(y, lane, o0, stats + 8192 + (size_t)rep*128, stats + 12288 + (size_t)rep*128);
    }
    return;
  }

  for (int o0 = 0; o0 < 128; o0 += 16) {
    float y[16];
#pragma unroll
    for (int k = 0; k < 16; ++k) {
      float a = b2[o0 + k];
#pragma unroll
      for (int c = 0; c < 64; ++c)
        a = fmaf(w2[(o0 + k)*64 + c], y1[c], a);
      y[k] = a;
    }
#pragma unroll
    for (int k = 0; k < 16; ++k)
      y[k] = fmaxf(fmaf(prm[256 + o0 + k], y[k], prm[384 + o0 + k]), 0.f);
    float m = fold_max16(y, lane);
    if (!(lane & 16))
      outp[(size_t)cs * 128 + o0 + (lane & 15)] = m;
  }
}

__global__ void finalize_kernel(const float* __restrict__ stats,
                                const float* __restrict__ g,
                                const float* __restrict__ beta,
                                float* __restrict__ pa, float* __restrict__ psh, int C)
{
  int c = threadIdx.x;
  if (c >= C) return;
  float s1 = 0.f, s2 = 0.f;
  for (int rr = 0; rr < NREP; ++rr) { s1 += stats[rr*C + c]; s2 += stats[NREP*C + rr*C + c]; }
  const float invn = 1.0f / (float)NROWS;
  float mean = s1 * invn;
  float var  = s2 * invn - mean * mean;
  float rs   = 1.0f / sqrtf(var + 1e-5f);
  float a    = g[c] * rs;
  pa[c]  = a;
  psh[c] = fmaf(-mean, a, beta[c]);
}

__global__ void zero_kernel(float* __restrict__ p, int n)
{
  int i = blockIdx.x * 256 + threadIdx.x;
  if (i < n) p[i] = 0.f;
}

// ======================== launch ========================
extern "C" void kernel_launch(void* const* d_in, const int* in_sizes, int n_in,
                              void* d_out, int out_size, void* d_ws, size_t ws_size,
                              hipStream_t stream)
{
  (void)in_sizes; (void)n_in; (void)out_size;
  const float* xyz   = (const float*)d_in[0];
  const float* feats = (const float*)d_in[1];
  const float* w0 = (const float*)d_in[2],  *b0 = (const float*)d_in[3];
  const float* g0 = (const float*)d_in[4],  *bt0 = (const float*)d_in[5];
  const float* w1 = (const float*)d_in[6],  *b1 = (const float*)d_in[7];
  const float* g1 = (const float*)d_in[8],  *bt1 = (const float*)d_in[9];
  const float* w2 = (const float*)d_in[10], *b2 = (const float*)d_in[11];
  const float* g2 = (const float*)d_in[12], *bt2 = (const float*)d_in[13];

  float* cents = (float*)d_out;                    // 8*2048*3
  float* outp  = cents + (size_t)NB * NS * 3;      // 8*2048*128

  int*   gidx  = (int*)d_ws;                                   // 2 MB
  float* stats = (float*)((char*)d_ws + (size_t)NROWS * 4);    // 16384 f32
  float* prm   = stats + 16384;                                // 512 f32
  float* actA  = (float*)((char*)d_ws + (4ull << 20));         // 134 MB
  float* actB  = actA + (size_t)NROWS * 64;                    // 134 MB
  const size_t ws_need = (4ull << 20) + 2ull * (size_t)NROWS * 64 * 4;

  fps_kernel<<<NB, 512, 0, stream>>>(xyz, cents);
  ballq_kernel<<<(NB*NS*64)/256, 256, 0, stream>>>(xyz, cents, gidx);
  zero_kernel<<<64, 256, 0, stream>>>(stats, 16384);

  if (ws_size >= ws_need) {
    // cached-activation path (no recompute)
    k1_kernel<<<NROWS/256, 256, 0, stream>>>(xyz, feats, cents, gidx, w0, b0, stats, actA);
    finalize_kernel<<<1, 128, 0, stream>>>(stats + 0, g0, bt0, prm + 0, prm + 64, 64);
    k2_kernel<<<NROWS/256, 256, 0, stream>>>(actA, w1, b1, prm, stats, actB);
    finalize_kernel<<<1, 128, 0, stream>>>(stats + 4096, g1, bt1, prm + 128, prm + 192, 64);
    k3_kernel<<<NROWS/256, 256, 0, stream>>>(actB, w2, b2, prm, stats);
    finalize_kernel<<<1, 128, 0, stream>>>(stats + 8192, g2, bt2, prm + 256, prm + 384, 128);
    k4_kernel<<<NROWS/256, 256, 0, stream>>>(actB, w2, b2, prm, outp);
  } else {
    // fallback: recompute chain (R3)
    chain_kernel<1><<<NROWS/256, 256, 0, stream>>>(xyz, feats, cents, gidx,
        w0, b0, w1, b1, w2, b2, prm, stats, outp);
    finalize_kernel<<<1, 128, 0, stream>>>(stats + 0, g0, bt0, prm + 0, prm + 64, 64);
    chain_kernel<2><<<NROWS/256, 256, 0, stream>>>(xyz, feats, cents, gidx,
        w0, b0, w1, b1, w2, b2, prm, stats, outp);
    finalize_kernel<<<1, 128, 0, stream>>>(stats + 4096, g1, bt1, prm + 128, prm + 192, 64);
    chain_kernel<3><<<NROWS/256, 256, 0, stream>>>(xyz, feats, cents, gidx,
        w0, b0, w1, b1, w2, b2, prm, stats, outp);
    finalize_kernel<<<1, 128, 0, stream>>>(stats + 8192, g2, bt2, prm + 256, prm + 384, 128);
    chain_kernel<4><<<NROWS/256, 256, 0, stream>>>(xyz, feats, cents, gidx,
        w0, b0, w1, b1, w2, b2, prm, stats, outp);
  }
}

// Round 5
// 3568.930 us; speedup vs baseline: 1.0824x; 1.0824x over previous
//
#include <hip/hip_runtime.h>
#include <cstdint>
#include <cstddef>

#define NPTS 8192
#define NB 8
#define NS 2048
#define KG 32
#define NROWS (NB*NS*KG)   // 524288
#define NREP 32            // stats atomic replication

// Distance with NO fma contraction: bitwise-identical to numpy f32
// ((dx*dx + dy*dy) + dz*dz).
__device__ __forceinline__ float dist2_exact(float ax, float ay, float az,
                                             float bx, float by, float bz)
{
#pragma clang fp contract(off)
  float dx = ax - bx;
  float dy = ay - by;
  float dz = az - bz;
  return dx * dx + dy * dy + dz * dz;
}

// ---- DPP pair-merge: (bm,ci) <- better of self and lane at CTRL offset.
// "better" = larger bm, ties -> smaller ci (jnp.argmax first-occurrence).
// bound_ctrl=false + old=self => sourceless lanes merge with themselves (no-op).
template<int CTRL>
__device__ __forceinline__ void dpp_merge(float& bm, unsigned& ci) {
  int b2i = __builtin_amdgcn_update_dpp(__float_as_int(bm), __float_as_int(bm),
                                        CTRL, 0xF, 0xF, false);
  int c2i = __builtin_amdgcn_update_dpp((int)ci, (int)ci, CTRL, 0xF, 0xF, false);
  float b2 = __int_as_float(b2i);
  unsigned c2 = (unsigned)c2i;
  bool take = (b2 > bm) || ((b2 == bm) && (c2 < ci));
  bm = take ? b2 : bm;
  ci = take ? c2 : ci;
}

// ======================== FPS ========================
// One block per batch, 512 threads x 16 pts in regs. Per-iter: 12 VALU/pt
// phase-1 (argmax pair via cndmask), wave reduce via DPP (VALU pipe, ~4cyc/step
// vs ds_bpermute ~100cyc), ONE barrier, 8-pair LDS merge, coord broadcast.
__launch_bounds__(512)
__global__ void fps_kernel(const float* __restrict__ xyz, float* __restrict__ cents)
{
  __shared__ float sx[NPTS], sy[NPTS], sz[NPTS];       // 96 KB
  __shared__ float smaxp[2][8];
  __shared__ unsigned scip[2][8];

  const int b = blockIdx.x;
  const int t = threadIdx.x;
  const float* base = xyz + (size_t)b * NPTS * 3;

  float px[16], py[16], pz[16], dmin[16];
  unsigned pidx[16];
#pragma unroll
  for (int j = 0; j < 16; ++j) {
    int i = j * 512 + t;
    float x = base[3*i+0], y = base[3*i+1], z = base[3*i+2];
    px[j] = x; py[j] = y; pz[j] = z;
    dmin[j] = 1e10f;
    pidx[j] = (unsigned)i;
    sx[i] = x; sy[i] = y; sz[i] = z;
  }

  float cx = base[0], cy = base[1], cz = base[2];
  if (t == 0) {
    float* c0 = cents + (size_t)b * NS * 3;
    c0[0] = cx; c0[1] = cy; c0[2] = cz;
  }
  __syncthreads();   // coords staged

  for (int it = 1; it < NS; ++it) {
    const int pb = it & 1;
    // ---- phase 1: update dmin + per-thread argmax pair (12 VALU/pt)
    float bm = -1.0f;
    unsigned ci = 0u;
#pragma unroll
    for (int j = 0; j < 16; ++j) {
      float d = dist2_exact(px[j], py[j], pz[j], cx, cy, cz);
      float m = fminf(dmin[j], d);
      dmin[j] = m;
      bool take = (m > bm);          // strict >: keeps earliest (j ascending)
      bm = take ? m : bm;
      ci = take ? pidx[j] : ci;
    }
    // ---- wave reduce via DPP (lane 63 ends with wave winner)
    dpp_merge<0x111>(bm, ci);   // row_shr:1
    dpp_merge<0x112>(bm, ci);   // row_shr:2
    dpp_merge<0x114>(bm, ci);   // row_shr:4
    dpp_merge<0x118>(bm, ci);   // row_shr:8
    dpp_merge<0x142>(bm, ci);   // row_bcast:15
    dpp_merge<0x143>(bm, ci);   // row_bcast:31
    float   wbm = __int_as_float(__builtin_amdgcn_readlane(__float_as_int(bm), 63));
    unsigned wci = (unsigned)__builtin_amdgcn_readlane((int)ci, 63);
    if ((t & 63) == 0) { smaxp[pb][t >> 6] = wbm; scip[pb][t >> 6] = wci; }
    __syncthreads();   // single barrier/iter (double-buffered partials)
    float bb = smaxp[pb][0];
    unsigned cc = scip[pb][0];
#pragma unroll
    for (int q = 1; q < 8; ++q) {
      float b2 = smaxp[pb][q];
      unsigned c2 = scip[pb][q];
      bool take = (b2 > bb) || ((b2 == bb) && (c2 < cc));
      bb = take ? b2 : bb;
      cc = take ? c2 : cc;
    }
    const int win = (int)cc;
    cx = sx[win]; cy = sy[win]; cz = sz[win];   // same-address broadcast
    if (t == 0) {
      float* cp = cents + ((size_t)b * NS + it) * 3;
      cp[0] = cx; cp[1] = cy; cp[2] = cz;
    }
  }
}

// ======================== Ball query ========================
__launch_bounds__(256)
__global__ void ballq_kernel(const float* __restrict__ xyz,
                             const float* __restrict__ cents,
                             int* __restrict__ gidx)
{
  const int gid  = blockIdx.x * 256 + threadIdx.x;
  const int w    = gid >> 6;          // centroid id 0..16383
  const int lane = gid & 63;
  const int b    = w >> 11;
  const float* base = xyz + (size_t)b * NPTS * 3;
  const float cx = cents[3*w+0], cy = cents[3*w+1], cz = cents[3*w+2];
  const float R2 = (float)(0.2 * 0.2);
  int* out = gidx + (size_t)w * KG;

  int filled = 0, first = -1;
  for (int c = 0; c < NPTS/64; ++c) {
    int i = (c << 6) | lane;
    float d = dist2_exact(base[3*i+0], base[3*i+1], base[3*i+2], cx, cy, cz);
    bool inb = (d <= R2);
    unsigned long long mask = __ballot(inb);
    if (first < 0 && mask) first = (c << 6) + (__ffsll((long long)mask) - 1);
    int pre  = __popcll(mask & ((1ull << lane) - 1ull));
    int slot = filled + pre;
    if (inb && slot < KG) out[slot] = i;
    filled += __popcll(mask);
    if (filled >= KG) break;
  }
  if (filled < KG && lane < KG && lane >= filled) out[lane] = first;
}

// ======================== shuffle fold-reductions ========================
template<int H>
__device__ __forceinline__ void fold_sum_step(float* a, int lane) {
#pragma unroll
  for (int q = 0; q < H; ++q) {
    float keep = (lane & H) ? a[q + H] : a[q];
    float send = (lane & H) ? a[q] : a[q + H];
    a[q] = keep + __shfl_xor(send, H, 64);
  }
}

__device__ __forceinline__ float fold_sum16(float* a, int lane) {
  fold_sum_step<8>(a, lane);
  fold_sum_step<4>(a, lane);
  fold_sum_step<2>(a, lane);
  fold_sum_step<1>(a, lane);
  float v = a[0];
  v += __shfl_xor(v, 16, 64);
  v += __shfl_xor(v, 32, 64);
  return v;
}

template<int H>
__device__ __forceinline__ void fold_max_step(float* a, int lane) {
#pragma unroll
  for (int q = 0; q < H; ++q) {
    float keep = (lane & H) ? a[q + H] : a[q];
    float send = (lane & H) ? a[q] : a[q + H];
    a[q] = fmaxf(keep, __shfl_xor(send, H, 64));
  }
}

__device__ __forceinline__ float fold_max16(float* a, int lane) {
  fold_max_step<8>(a, lane);
  fold_max_step<4>(a, lane);
  fold_max_step<2>(a, lane);
  fold_max_step<1>(a, lane);
  float v = a[0];
  v = fmaxf(v, __shfl_xor(v, 16, 64));   // merge the two 16-lane halves of the 32-group
  return v;
}

template<int H>
__device__ __forceinline__ void fold_min_step(float* a, int lane) {
#pragma unroll
  for (int q = 0; q < H; ++q) {
    float keep = (lane & H) ? a[q + H] : a[q];
    float send = (lane & H) ? a[q] : a[q + H];
    a[q] = fminf(keep, __shfl_xor(send, H, 64));
  }
}

__device__ __forceinline__ float fold_min16(float* a, int lane) {
  fold_min_step<8>(a, lane);
  fold_min_step<4>(a, lane);
  fold_min_step<2>(a, lane);
  fold_min_step<1>(a, lane);
  float v = a[0];
  v = fminf(v, __shfl_xor(v, 16, 64));
  return v;
}

// s1/s2 stats of 16 channels. Destroys y.
__device__ __forceinline__ void stats16(float* y, int lane, int o0,
                                        float* __restrict__ gs1,
                                        float* __restrict__ gs2)
{
  float sq[16];
#pragma unroll
  for (int q = 0; q < 16; ++q) sq[q] = y[q] * y[q];
  float s1 = fold_sum16(y, lane);
  float s2 = fold_sum16(sq, lane);
  if (lane < 16)       atomicAdd(&gs1[o0 + lane], s1);
  else if (lane < 32)  atomicAdd(&gs2[o0 + (lane & 15)], s2);
}

// k-group (32-row) max/min of y -> zmax/zmin[cs*128 + o0 + ch]. Destroys copies.
__device__ __forceinline__ void minmax16(const float* y, int lane, int o0, int cs,
                                         float* __restrict__ zmax,
                                         float* __restrict__ zmin)
{
  float ymx[16], ymn[16];
#pragma unroll
  for (int q = 0; q < 16; ++q) { ymx[q] = y[q]; ymn[q] = y[q]; }
  float mx = fold_max16(ymx, lane);
  float mn = fold_min16(ymn, lane);
  if (!(lane & 16)) {
    zmax[(size_t)cs * 128 + o0 + (lane & 15)] = mx;
    zmin[(size_t)cs * 128 + o0 + (lane & 15)] = mn;
  }
}

// ---- bf16 helpers (RNE pack, shift unpack)
__device__ __forceinline__ unsigned short f2b(float f) {
  unsigned b = __float_as_uint(f);
  return (unsigned short)((b + 0x7FFFu + ((b >> 16) & 1u)) >> 16);
}
__device__ __forceinline__ float b2f(unsigned short h) {
  return __uint_as_float(((unsigned)h) << 16);
}

// ======================== Tier A: bf16-cached chain ========================
// actL: channel-major [64][NROWS] bf16 (coalesced both directions), reused
// in place for L1 (per-thread read-all-then-write-all, column-disjoint).
// stats layout (floats): L0 s1@0 s2@2048 | L1 s1@4096 s2@6144 | L2 s1@8192 s2@12288
// prm: a0@0 sh0@64 a1@128 sh1@192 a2@256 sh2@384.

__launch_bounds__(256, 3)
__global__ void k1_kernel(const float* __restrict__ xyz, const float* __restrict__ feats,
                          const float* __restrict__ cents, const int* __restrict__ gidx,
                          const float* __restrict__ w0, const float* __restrict__ b0,
                          float* __restrict__ stats, unsigned short* __restrict__ actL)
{
  const int t = threadIdx.x, lane = t & 63;
  const int r = blockIdx.x * 256 + t;
  const int b = r >> 16, cs = r >> 5;
  const int i = gidx[r];
  const int rep = (blockIdx.x * 4 + (t >> 6)) & (NREP - 1);
  const float* pp = xyz + ((size_t)(b << 13) + i) * 3;
  const float* cc = cents + (size_t)cs * 3;
  const float* fb = feats + (((size_t)(b << 13) + i) << 6);

  float xin[67];
  xin[0] = pp[0] - cc[0]; xin[1] = pp[1] - cc[1]; xin[2] = pp[2] - cc[2];
  const float4* f4 = (const float4*)fb;
#pragma unroll
  for (int q = 0; q < 16; ++q) {
    float4 v = f4[q];
    xin[3+4*q+0] = v.x; xin[3+4*q+1] = v.y; xin[3+4*q+2] = v.z; xin[3+4*q+3] = v.w;
  }

  for (int o0 = 0; o0 < 64; o0 += 16) {     // rolled: I$-resident body
    float y[16];
#pragma unroll
    for (int k = 0; k < 16; ++k) {
      float a = b0[o0 + k];
#pragma unroll
      for (int c = 0; c < 67; ++c)
        a = fmaf(w0[(o0 + k)*67 + c], xin[c], a);
      y[k] = a;
    }
#pragma unroll
    for (int k = 0; k < 16; ++k)
      actL[(size_t)(o0 + k) * NROWS + r] = f2b(y[k]);
    stats16(y, lane, o0, stats + (size_t)rep*64, stats + 2048 + (size_t)rep*64);
  }
}

__launch_bounds__(256, 3)
__global__ void k2_kernel(unsigned short* __restrict__ actL,
                          const float* __restrict__ w1, const float* __restrict__ b1,
                          const float* __restrict__ prm,
                          float* __restrict__ stats)
{
  const int t = threadIdx.x, lane = t & 63;
  const int r = blockIdx.x * 256 + t;
  const int rep = (blockIdx.x * 4 + (t >> 6)) & (NREP - 1);

  float x[64];
#pragma unroll
  for (int c = 0; c < 64; ++c)
    x[c] = b2f(actL[(size_t)c * NROWS + r]);
#pragma unroll
  for (int c = 0; c < 64; ++c)
    x[c] = fmaxf(fmaf(prm[c], x[c], prm[64 + c]), 0.f);

  for (int o0 = 0; o0 < 64; o0 += 16) {
    float y[16];
#pragma unroll
    for (int k = 0; k < 16; ++k) {
      float a = b1[o0 + k];
#pragma unroll
      for (int c = 0; c < 64; ++c)
        a = fmaf(w1[(o0 + k)*64 + c], x[c], a);
      y[k] = a;
    }
#pragma unroll
    for (int k = 0; k < 16; ++k)
      actL[(size_t)(o0 + k) * NROWS + r] = f2b(y[k]);   // in-place: col r only
    stats16(y, lane, o0, stats + 4096 + (size_t)rep*64, stats + 6144 + (size_t)rep*64);
  }
}

__launch_bounds__(256, 3)
__global__ void k3_kernel(const unsigned short* __restrict__ actL,
                          const float* __restrict__ w2, const float* __restrict__ b2,
                          const float* __restrict__ prm,
                          float* __restrict__ stats,
                          float* __restrict__ zmax, float* __restrict__ zmin)
{
  const int t = threadIdx.x, lane = t & 63;
  const int r = blockIdx.x * 256 + t;
  const int cs = r >> 5;
  const int rep = (blockIdx.x * 4 + (t >> 6)) & (NREP - 1);

  float x[64];
#pragma unroll
  for (int c = 0; c < 64; ++c)
    x[c] = b2f(actL[(size_t)c * NROWS + r]);
#pragma unroll
  for (int c = 0; c < 64; ++c)
    x[c] = fmaxf(fmaf(prm[128 + c], x[c], prm[192 + c]), 0.f);

  for (int o0 = 0; o0 < 128; o0 += 16) {
    float y[16];
#pragma unroll
    for (int k = 0; k < 16; ++k) {
      float a = b2[o0 + k];
#pragma unroll
      for (int c = 0; c < 64; ++c)
        a = fmaf(w2[(o0 + k)*64 + c], x[c], a);
      y[k] = a;
    }
    minmax16(y, lane, o0, cs, zmax, zmin);
    stats16(y, lane, o0, stats + 8192 + (size_t)rep*128, stats + 12288 + (size_t)rep*128);
  }
}

// out = relu(a*zsel + sh): max_k relu(a*z_k+sh) == relu(a*(a>=0?zmax:zmin)+sh)
// (affine+relu monotone; min branch guards negative gamma).
__launch_bounds__(256)
__global__ void outfin_kernel(const float* __restrict__ zmax,
                              const float* __restrict__ zmin,
                              const float* __restrict__ prm,
                              float* __restrict__ outp)
{
  int i = blockIdx.x * 256 + threadIdx.x;      // 16384*128 total
  int ch = i & 127;
  float a = prm[256 + ch], sh = prm[384 + ch];
  float z = (a >= 0.f) ? zmax[i] : zmin[i];
  outp[i] = fmaxf(fmaf(a, z, sh), 0.f);
}

// ======================== Tier B/C: recompute chain ========================
// MODE 1/2: stats passes. MODE 5: recompute L0,L1 + dense2 + stats2 + minmax
// (tier B; replaces modes 3&4). MODE 3/4: tier C (R3 proven).
template<int MODE>
__launch_bounds__(256, (MODE <= 2 ? 4 : 2))
__global__ void chain_kernel(const float* __restrict__ xyz,
                             const float* __restrict__ feats,
                             const float* __restrict__ cents,
                             const int* __restrict__ gidx,
                             const float* __restrict__ w0, const float* __restrict__ b0,
                             const float* __restrict__ w1, const float* __restrict__ b1,
                             const float* __restrict__ w2, const float* __restrict__ b2,
                             const float* __restrict__ prm,
                             float* __restrict__ stats,
                             float* __restrict__ outp,
                             float* __restrict__ zmax, float* __restrict__ zmin)
{
  const int t    = threadIdx.x;
  const int lane = t & 63;
  const int r    = blockIdx.x * 256 + t;
  const int b    = r >> 16;
  const int cs   = r >> 5;
  const int i    = gidx[r];
  const int rep  = (blockIdx.x * 4 + (t >> 6)) & (NREP - 1);

  const float* pp = xyz + ((size_t)(b << 13) + i) * 3;
  const float* cc = cents + (size_t)cs * 3;
  const float* fb = feats + (((size_t)(b << 13) + i) << 6);

  float acc[64];
  {
    float c0 = pp[0] - cc[0], c1 = pp[1] - cc[1], c2 = pp[2] - cc[2];
#pragma unroll
    for (int o = 0; o < 64; ++o)
      acc[o] = fmaf(w0[o*67+2], c2, fmaf(w0[o*67+1], c1, fmaf(w0[o*67+0], c0, b0[o])));
  }
  for (int c0 = 0; c0 < 64; c0 += 16) {
    float xc[16];
    const float4* f4 = (const float4*)(fb + c0);
    float4 v0 = f4[0], v1 = f4[1], v2 = f4[2], v3 = f4[3];
    xc[0]=v0.x; xc[1]=v0.y; xc[2]=v0.z; xc[3]=v0.w;
    xc[4]=v1.x; xc[5]=v1.y; xc[6]=v1.z; xc[7]=v1.w;
    xc[8]=v2.x; xc[9]=v2.y; xc[10]=v2.z; xc[11]=v2.w;
    xc[12]=v3.x; xc[13]=v3.y; xc[14]=v3.z; xc[15]=v3.w;
#pragma unroll
    for (int o = 0; o < 64; ++o) {
      float a = acc[o];
#pragma unroll
      for (int ci = 0; ci < 16; ++ci)
        a = fmaf(w0[o*67 + 3 + c0 + ci], xc[ci], a);
      acc[o] = a;
    }
  }

  if (MODE == 1) {
#pragma unroll
    for (int o0 = 0; o0 < 64; o0 += 16) {
      float y[16];
#pragma unroll
      for (int q = 0; q < 16; ++q) y[q] = acc[o0 + q];
      stats16(y, lane, o0, stats + (size_t)rep*64, stats + 2048 + (size_t)rep*64);
    }
    return;
  }

#pragma unroll
  for (int o = 0; o < 64; ++o)
    acc[o] = fmaxf(fmaf(prm[o], acc[o], prm[64 + o]), 0.f);

  if (MODE == 2) {
    for (int o0 = 0; o0 < 64; o0 += 16) {
      float y[16];
#pragma unroll
      for (int k = 0; k < 16; ++k) {
        float a = b1[o0 + k];
#pragma unroll
        for (int c = 0; c < 64; ++c)
          a = fmaf(w1[(o0 + k)*64 + c], acc[c], a);
        y[k] = a;
      }
      stats16(y, lane, o0, stats + 4096 + (size_t)rep*64, stats + 6144 + (size_t)rep*64);
    }
    return;
  }

  float y1[64];
#pragma unroll
  for (int o = 0; o < 64; ++o) {
    float a = b1[o];
#pragma unroll
    for (int c = 0; c < 64; ++c)
      a = fmaf(w1[o*64 + c], acc[c], a);
    y1[o] = a;
  }
#pragma unroll
  for (int o = 0; o < 64; ++o)
    y1[o] = fmaxf(fmaf(prm[128 + o], y1[o], prm[192 + o]), 0.f);

  if (MODE == 3 || MODE == 5) {
    for (int o0 = 0; o0 < 128; o0 += 16) {
      float y[16];
#pragma unroll
      for (int k = 0; k < 16; ++k) {
        float a = b2[o0 + k];
#pragma unroll
        for (int c = 0; c < 64; ++c)
          a = fmaf(w2[(o0 + k)*64 + c], y1[c], a);
        y[k] = a;
      }
      if (MODE == 5) minmax16(y, lane, o0, cs, zmax, zmin);
      stats16(y, lane, o0, stats + 8192 + (size_t)rep*128, stats + 12288 + (size_t)rep*128);
    }
    return;
  }

  // MODE 4 (tier C): norm2+relu+maxpool
  for (int o0 = 0; o0 < 128; o0 += 16) {
    float y[16];
#pragma unroll
    for (int k = 0; k < 16; ++k) {
      float a = b2[o0 + k];
#pragma unroll
      for (int c = 0; c < 64; ++c)
        a = fmaf(w2[(o0 + k)*64 + c], y1[c], a);
      y[k] = a;
    }
#pragma unroll
    for (int k = 0; k < 16; ++k)
      y[k] = fmaxf(fmaf(prm[256 + o0 + k], y[k], prm[384 + o0 + k]), 0.f);
    float m = fold_max16(y, lane);
    if (!(lane & 16))
      outp[(size_t)cs * 128 + o0 + (lane & 15)] = m;
  }
}

__global__ void finalize_kernel(const float* __restrict__ stats,
                                const float* __restrict__ g,
                                const float* __restrict__ beta,
                                float* __restrict__ pa, float* __restrict__ psh, int C)
{
  int c = threadIdx.x;
  if (c >= C) return;
  float s1 = 0.f, s2 = 0.f;
  for (int rr = 0; rr < NREP; ++rr) { s1 += stats[rr*C + c]; s2 += stats[NREP*C + rr*C + c]; }
  const float invn = 1.0f / (float)NROWS;
  float mean = s1 * invn;
  float var  = s2 * invn - mean * mean;
  float rs   = 1.0f / sqrtf(var + 1e-5f);
  float a    = g[c] * rs;
  pa[c]  = a;
  psh[c] = fmaf(-mean, a, beta[c]);
}

__global__ void zero_kernel(float* __restrict__ p, int n)
{
  int i = blockIdx.x * 256 + threadIdx.x;
  if (i < n) p[i] = 0.f;
}

// ======================== launch ========================
extern "C" void kernel_launch(void* const* d_in, const int* in_sizes, int n_in,
                              void* d_out, int out_size, void* d_ws, size_t ws_size,
                              hipStream_t stream)
{
  (void)in_sizes; (void)n_in; (void)out_size;
  const float* xyz   = (const float*)d_in[0];
  const float* feats = (const float*)d_in[1];
  const float* w0 = (const float*)d_in[2],  *b0 = (const float*)d_in[3];
  const float* g0 = (const float*)d_in[4],  *bt0 = (const float*)d_in[5];
  const float* w1 = (const float*)d_in[6],  *b1 = (const float*)d_in[7];
  const float* g1 = (const float*)d_in[8],  *bt1 = (const float*)d_in[9];
  const float* w2 = (const float*)d_in[10], *b2 = (const float*)d_in[11];
  const float* g2 = (const float*)d_in[12], *bt2 = (const float*)d_in[13];

  float* cents = (float*)d_out;                    // 8*2048*3
  float* outp  = cents + (size_t)NB * NS * 3;      // 8*2048*128

  int*   gidx  = (int*)d_ws;                                   // 2 MiB
  float* stats = (float*)((char*)d_ws + (size_t)NROWS * 4);    // 16384 f32
  float* prm   = stats + 16384;                                // 512 f32
  float* zmax  = (float*)((char*)d_ws + (4ull  << 20));        // 8 MiB
  float* zmin  = (float*)((char*)d_ws + (12ull << 20));        // 8 MiB
  unsigned short* actL = (unsigned short*)((char*)d_ws + (20ull << 20)); // 64 MiB
  const size_t need_A = (20ull << 20) + (size_t)NROWS * 64 * 2;
  const size_t need_B = (20ull << 20);

  fps_kernel<<<NB, 512, 0, stream>>>(xyz, cents);
  ballq_kernel<<<(NB*NS*64)/256, 256, 0, stream>>>(xyz, cents, gidx);
  zero_kernel<<<64, 256, 0, stream>>>(stats, 16384);

  if (ws_size >= need_A) {
    k1_kernel<<<NROWS/256, 256, 0, stream>>>(xyz, feats, cents, gidx, w0, b0, stats, actL);
    finalize_kernel<<<1, 128, 0, stream>>>(stats + 0, g0, bt0, prm + 0, prm + 64, 64);
    k2_kernel<<<NROWS/256, 256, 0, stream>>>(actL, w1, b1, prm, stats);
    finalize_kernel<<<1, 128, 0, stream>>>(stats + 4096, g1, bt1, prm + 128, prm + 192, 64);
    k3_kernel<<<NROWS/256, 256, 0, stream>>>(actL, w2, b2, prm, stats, zmax, zmin);
    finalize_kernel<<<1, 128, 0, stream>>>(stats + 8192, g2, bt2, prm + 256, prm + 384, 128);
    outfin_kernel<<<(16384*128)/256, 256, 0, stream>>>(zmax, zmin, prm, outp);
  } else if (ws_size >= need_B) {
    chain_kernel<1><<<NROWS/256, 256, 0, stream>>>(xyz, feats, cents, gidx,
        w0, b0, w1, b1, w2, b2, prm, stats, outp, zmax, zmin);
    finalize_kernel<<<1, 128, 0, stream>>>(stats + 0, g0, bt0, prm + 0, prm + 64, 64);
    chain_kernel<2><<<NROWS/256, 256, 0, stream>>>(xyz, feats, cents, gidx,
        w0, b0, w1, b1, w2, b2, prm, stats, outp, zmax, zmin);
    finalize_kernel<<<1, 128, 0, stream>>>(stats + 4096, g1, bt1, prm + 128, prm + 192, 64);
    chain_kernel<5><<<NROWS/256, 256, 0, stream>>>(xyz, feats, cents, gidx,
        w0, b0, w1, b1, w2, b2, prm, stats, outp, zmax, zmin);
    finalize_kernel<<<1, 128, 0, stream>>>(stats + 8192, g2, bt2, prm + 256, prm + 384, 128);
    outfin_kernel<<<(16384*128)/256, 256, 0, stream>>>(zmax, zmin, prm, outp);
  } else {
    chain_kernel<1><<<NROWS/256, 256, 0, stream>>>(xyz, feats, cents, gidx,
        w0, b0, w1, b1, w2, b2, prm, stats, outp, zmax, zmin);
    finalize_kernel<<<1, 128, 0, stream>>>(stats + 0, g0, bt0, prm + 0, prm + 64, 64);
    chain_kernel<2><<<NROWS/256, 256, 0, stream>>>(xyz, feats, cents, gidx,
        w0, b0, w1, b1, w2, b2, prm, stats, outp, zmax, zmin);
    finalize_kernel<<<1, 128, 0, stream>>>(stats + 4096, g1, bt1, prm + 128, prm + 192, 64);
    chain_kernel<3><<<NROWS/256, 256, 0, stream>>>(xyz, feats, cents, gidx,
        w0, b0, w1, b1, w2, b2, prm, stats, outp, zmax, zmin);
    finalize_kernel<<<1, 128, 0, stream>>>(stats + 8192, g2, bt2, prm + 256, prm + 384, 128);
    chain_kernel<4><<<NROWS/256, 256, 0, stream>>>(xyz, feats, cents, gidx,
        w0, b0, w1, b1, w2, b2, prm, stats, outp, zmax, zmin);
  }
}